// Round 1
// baseline (1377.231 us; speedup 1.0000x reference)
//
#include <hip/hip_runtime.h>
#include <stdint.h>

typedef __attribute__((ext_vector_type(8))) short short8;
typedef __attribute__((ext_vector_type(4))) float f32x4;
typedef __attribute__((ext_vector_type(4))) unsigned short us4;

__device__ inline unsigned short f2bf(float f) {
    unsigned u = __float_as_uint(f);
    u = (u + 0x7FFFu + ((u >> 16) & 1u)) >> 16;   // RNE
    return (unsigned short)u;
}

// ---------------- elementwise convert x -> bf16 ----------------
__global__ __launch_bounds__(256) void cvt_x_kernel(const float* __restrict__ in,
                                                    unsigned short* __restrict__ out, int n4) {
    int i = blockIdx.x * 256 + threadIdx.x;
    if (i >= n4) return;
    float4 v = reinterpret_cast<const float4*>(in)[i];
    us4 o = { f2bf(v.x), f2bf(v.y), f2bf(v.z), f2bf(v.w) };
    reinterpret_cast<us4*>(out)[i] = o;
}

// ---------------- transpose + convert gate_w [K,N] f32 -> WT [N,K] bf16 ----------------
__global__ __launch_bounds__(256) void transpose_w_kernel(const float* __restrict__ W,
                                                          unsigned short* __restrict__ WT,
                                                          int K, int N) {
    __shared__ float tile[32][33];
    int bn = blockIdx.x * 32;
    int bk = blockIdx.y * 32;
    int tx = threadIdx.x & 31;
    int ty = threadIdx.x >> 5;   // 0..7
#pragma unroll
    for (int j = 0; j < 32; j += 8)
        tile[ty + j][tx] = W[(long long)(bk + ty + j) * N + bn + tx];
    __syncthreads();
#pragma unroll
    for (int j = 0; j < 32; j += 8)
        WT[(long long)(bn + ty + j) * K + bk + tx] = f2bf(tile[tx][ty + j]);
}

// ---------------- block reduction (sum, sumsq) over 256 threads ----------------
__device__ inline void block_reduce2(float& s, float& q) {
#pragma unroll
    for (int o = 32; o > 0; o >>= 1) {
        s += __shfl_xor(s, o, 64);
        q += __shfl_xor(q, o, 64);
    }
    __shared__ float sh[8];
    int w = threadIdx.x >> 6;
    if ((threadIdx.x & 63) == 0) { sh[w] = s; sh[4 + w] = q; }
    __syncthreads();
    s = (sh[0] + sh[1]) + (sh[2] + sh[3]);
    q = (sh[4] + sh[5]) + (sh[6] + sh[7]);
}

// ---------------- row LayerNorm, D=2048, one block per row (works in-place) ----------------
__global__ __launch_bounds__(256) void ln_rows_kernel(const float* __restrict__ in, long long in_stride,
                                                      float* __restrict__ out, long long out_stride,
                                                      const float* __restrict__ gamma,
                                                      const float* __restrict__ beta) {
    const float* p = in + (long long)blockIdx.x * in_stride;
    float* q = out + (long long)blockIdx.x * out_stride;
    int t = threadIdx.x;
    float4 a = reinterpret_cast<const float4*>(p)[t];
    float4 c = reinterpret_cast<const float4*>(p)[t + 256];
    float s  = (a.x + a.y) + (a.z + a.w) + (c.x + c.y) + (c.z + c.w);
    float ss = a.x*a.x + a.y*a.y + a.z*a.z + a.w*a.w
             + c.x*c.x + c.y*c.y + c.z*c.z + c.w*c.w;
    block_reduce2(s, ss);
    const float inv = 1.0f / 2048.0f;
    float mu = s * inv;
    float var = ss * inv - mu * mu;
    float rs = rsqrtf(var + 1e-6f);
    float4 g0 = reinterpret_cast<const float4*>(gamma)[t];
    float4 g1 = reinterpret_cast<const float4*>(gamma)[t + 256];
    float4 b0 = reinterpret_cast<const float4*>(beta)[t];
    float4 b1 = reinterpret_cast<const float4*>(beta)[t + 256];
    float4 o0, o1;
    o0.x = (a.x - mu) * rs * g0.x + b0.x;
    o0.y = (a.y - mu) * rs * g0.y + b0.y;
    o0.z = (a.z - mu) * rs * g0.z + b0.z;
    o0.w = (a.w - mu) * rs * g0.w + b0.w;
    o1.x = (c.x - mu) * rs * g1.x + b1.x;
    o1.y = (c.y - mu) * rs * g1.y + b1.y;
    o1.z = (c.z - mu) * rs * g1.z + b1.z;
    o1.w = (c.w - mu) * rs * g1.w + b1.w;
    reinterpret_cast<float4*>(q)[t] = o0;
    reinterpret_cast<float4*>(q)[t + 256] = o1;
}

// ---------------- bias init / add for the 4-row thought buffers ----------------
__global__ __launch_bounds__(256) void set_bias4_kernel(float* __restrict__ out,
                                                        const float* __restrict__ bias, int N) {
    int i = blockIdx.x * 256 + threadIdx.x;
    if (i < N) {
        float v = bias[i];
        out[i] = v; out[N + i] = v; out[2 * N + i] = v; out[3 * N + i] = v;
    }
}
__global__ __launch_bounds__(256) void add_bias4_kernel(float* __restrict__ out,
                                                        const float* __restrict__ bias, int N) {
    int i = blockIdx.x * 256 + threadIdx.x;
    if (i < N) {
        float v = bias[i];
        out[i] += v; out[N + i] += v; out[2 * N + i] += v; out[3 * N + i] += v;
    }
}

// ---------------- batch-4 GEMV: out[4][N] += in[4][K] @ W[K][N] (K-chunked, atomic) ----------------
__global__ __launch_bounds__(256) void gemv4_kernel(const float* __restrict__ in,
                                                    const float* __restrict__ W,
                                                    float* __restrict__ out, int K, int N) {
    int n = blockIdx.x * 256 + threadIdx.x;
    int kc = K / gridDim.y;
    int k0 = blockIdx.y * kc;
    const float* i0 = in;
    const float* i1 = in + K;
    const float* i2 = in + 2 * K;
    const float* i3 = in + 3 * K;
    float a0 = 0.f, a1 = 0.f, a2 = 0.f, a3 = 0.f;
    for (int k = k0; k < k0 + kc; ++k) {
        float w = W[(long long)k * N + n];
        a0 = fmaf(i0[k], w, a0);
        a1 = fmaf(i1[k], w, a1);
        a2 = fmaf(i2[k], w, a2);
        a3 = fmaf(i3[k], w, a3);
    }
    atomicAdd(&out[n], a0);
    atomicAdd(&out[N + n], a1);
    atomicAdd(&out[2 * N + n], a2);
    atomicAdd(&out[3 * N + n], a3);
}

// ---------------- exact GELU on hbuf ----------------
__global__ __launch_bounds__(256) void gelu_kernel(float* __restrict__ h, int n) {
    int i = blockIdx.x * 256 + threadIdx.x;
    if (i < n) {
        float v = h[i];
        h[i] = 0.5f * v * (1.0f + erff(v * 0.70710678118654752f));
    }
}

// ---------------- big fused kernel: pre = x + sigmoid(x@gate_w + gate_b) * bcast ----------------
// A = x as bf16 [M,K]; BT = gate_w^T as bf16 [N,K]; xf = original x f32; pre = d_out
__global__ __launch_bounds__(256) void gate_gemm_kernel(const unsigned short* __restrict__ A,
                                                        const unsigned short* __restrict__ BT,
                                                        const float* __restrict__ xf,
                                                        const float* __restrict__ gate_b,
                                                        const float* __restrict__ bcast,
                                                        float* __restrict__ pre,
                                                        int M, int N, int K) {
    __shared__ unsigned short As[128 * 32];
    __shared__ unsigned short Bs[128 * 32];
    const int tid = threadIdx.x;
    const int lane = tid & 63;
    const int wave = tid >> 6;
    const int wr = wave >> 1, wc = wave & 1;          // 2x2 waves, each 64x64
    const long long row0 = (long long)blockIdx.x * 128;
    const long long col0 = (long long)blockIdx.y * 128;

    // staging: 512 chunks of 16B per tile; thread handles chunks tid and tid+256
    const int c0 = tid, c1 = tid + 256;
    const int ar0 = c0 >> 2, ak0 = (c0 & 3) * 8;
    const int ar1 = c1 >> 2, ak1 = (c1 & 3) * 8;
    const unsigned short* pa0 = A + (row0 + ar0) * K + ak0;
    const unsigned short* pa1 = A + (row0 + ar1) * K + ak1;
    const unsigned short* pb0 = BT + (col0 + ar0) * K + ak0;
    const unsigned short* pb1 = BT + (col0 + ar1) * K + ak1;

    f32x4 acc[4][4];
#pragma unroll
    for (int i = 0; i < 4; ++i)
#pragma unroll
        for (int j = 0; j < 4; ++j)
#pragma unroll
            for (int r = 0; r < 4; ++r) acc[i][j][r] = 0.f;

    const int r16 = lane & 15, kq = lane >> 4;

    for (int k0i = 0; k0i < K; k0i += 32) {
        short8 va0 = *reinterpret_cast<const short8*>(pa0 + k0i);
        short8 va1 = *reinterpret_cast<const short8*>(pa1 + k0i);
        short8 vb0 = *reinterpret_cast<const short8*>(pb0 + k0i);
        short8 vb1 = *reinterpret_cast<const short8*>(pb1 + k0i);
        __syncthreads();   // previous iteration's LDS reads complete
        *reinterpret_cast<short8*>(&As[c0 * 8]) = va0;
        *reinterpret_cast<short8*>(&As[c1 * 8]) = va1;
        *reinterpret_cast<short8*>(&Bs[c0 * 8]) = vb0;
        *reinterpret_cast<short8*>(&Bs[c1 * 8]) = vb1;
        __syncthreads();
        short8 af[4], bf[4];
#pragma unroll
        for (int mi = 0; mi < 4; ++mi)
            af[mi] = *reinterpret_cast<const short8*>(&As[(wr * 64 + mi * 16 + r16) * 32 + kq * 8]);
#pragma unroll
        for (int ni = 0; ni < 4; ++ni)
            bf[ni] = *reinterpret_cast<const short8*>(&Bs[(wc * 64 + ni * 16 + r16) * 32 + kq * 8]);
#pragma unroll
        for (int mi = 0; mi < 4; ++mi)
#pragma unroll
            for (int ni = 0; ni < 4; ++ni)
                acc[mi][ni] = __builtin_amdgcn_mfma_f32_16x16x32_bf16(af[mi], bf[ni], acc[mi][ni], 0, 0, 0);
    }

    // epilogue: sigmoid gate, residual add, broadcast thought
#pragma unroll
    for (int mi = 0; mi < 4; ++mi) {
#pragma unroll
        for (int ni = 0; ni < 4; ++ni) {
            const long long col = col0 + wc * 64 + ni * 16 + r16;
            const float gb = gate_b[col];
#pragma unroll
            for (int r = 0; r < 4; ++r) {
                const long long row = row0 + wr * 64 + mi * 16 + kq * 4 + r;
                const float v = acc[mi][ni][r] + gb;
                const float g = 1.0f / (1.0f + __expf(-v));
                const int b = (int)(row >> 12);           // L = 4096
                const long long off = row * N + col;
                pre[off] = xf[off] + g * bcast[(long long)b * N + col];
            }
        }
    }
}

extern "C" void kernel_launch(void* const* d_in, const int* in_sizes, int n_in,
                              void* d_out, int out_size, void* d_ws, size_t ws_size,
                              hipStream_t stream) {
    const float* x         = (const float*)d_in[0];
    const float* in_gamma  = (const float*)d_in[1];
    const float* in_beta   = (const float*)d_in[2];
    const float* agg_w     = (const float*)d_in[3];
    const float* agg_b     = (const float*)d_in[4];
    const float* pn_gamma  = (const float*)d_in[5];
    const float* pn_beta   = (const float*)d_in[6];
    const float* d1_w      = (const float*)d_in[7];
    const float* d1_b      = (const float*)d_in[8];
    const float* d2_w      = (const float*)d_in[9];
    const float* d2_b      = (const float*)d_in[10];
    const float* bc_w      = (const float*)d_in[11];
    const float* bc_b      = (const float*)d_in[12];
    const float* gate_w    = (const float*)d_in[13];
    const float* gate_b    = (const float*)d_in[14];
    const float* out_gamma = (const float*)d_in[15];
    const float* out_beta  = (const float*)d_in[16];

    const int B = 4, L = 4096, D = 2048, H = 8192;
    const int M = B * L;                       // 16384
    float* out = (float*)d_out;

    char* ws = (char*)d_ws;
    unsigned short* xb  = (unsigned short*)ws;                 // 64 MB  bf16 x
    unsigned short* gwT = (unsigned short*)(ws + 67108864);    //  8 MB  bf16 gate_w^T
    float* tln   = (float*)(ws + 75497472);                    // [4][D]
    float* tbuf  = tln + 4 * D;                                // [4][D] thought
    float* hbuf  = tbuf + 4 * D;                               // [4][H]
    float* bcast = hbuf + 4 * H;                               // [4][D]

    // ---- thought chain first (keeps weights L3-warm across the 4 steps) ----
    ln_rows_kernel<<<dim3(B), dim3(256), 0, stream>>>(
        x + (long long)(L - 1) * D, (long long)L * D, tln, (long long)D, in_gamma, in_beta);
    set_bias4_kernel<<<dim3(D / 256), dim3(256), 0, stream>>>(tbuf, agg_b, D);
    gemv4_kernel<<<dim3(D / 256, 16), dim3(256), 0, stream>>>(tln, agg_w, tbuf, D, D);

    for (int s = 0; s < 4; ++s) {
        ln_rows_kernel<<<dim3(B), dim3(256), 0, stream>>>(
            tbuf, (long long)D, tln, (long long)D, pn_gamma, pn_beta);
        set_bias4_kernel<<<dim3(H / 256), dim3(256), 0, stream>>>(hbuf, d1_b, H);
        gemv4_kernel<<<dim3(H / 256, 8), dim3(256), 0, stream>>>(tln, d1_w, hbuf, D, H);
        gelu_kernel<<<dim3(B * H / 256), dim3(256), 0, stream>>>(hbuf, B * H);
        add_bias4_kernel<<<dim3(D / 256), dim3(256), 0, stream>>>(tbuf, d2_b, D);
        gemv4_kernel<<<dim3(D / 256, 16), dim3(256), 0, stream>>>(hbuf, d2_w, tbuf, H, D);
    }
    set_bias4_kernel<<<dim3(D / 256), dim3(256), 0, stream>>>(bcast, bc_b, D);
    gemv4_kernel<<<dim3(D / 256, 16), dim3(256), 0, stream>>>(tbuf, bc_w, bcast, D, D);

    // ---- prepare bf16 operands for the big GEMM ----
    cvt_x_kernel<<<dim3((M * D / 4) / 256), dim3(256), 0, stream>>>(x, xb, M * D / 4);
    transpose_w_kernel<<<dim3(D / 32, D / 32), dim3(256), 0, stream>>>(gate_w, gwT, D, D);

    // ---- fused gate GEMM + sigmoid + residual + broadcast -> d_out (pre-LN) ----
    gate_gemm_kernel<<<dim3(M / 128, D / 128), dim3(256), 0, stream>>>(
        xb, gwT, x, gate_b, bcast, out, M, D, D);

    // ---- final LayerNorm in-place on d_out ----
    ln_rows_kernel<<<dim3(M), dim3(256), 0, stream>>>(
        out, (long long)D, out, (long long)D, out_gamma, out_beta);
}

// Round 3
// 649.104 us; speedup vs baseline: 2.1217x; 2.1217x over previous
//
#include <hip/hip_runtime.h>
#include <stdint.h>

typedef __attribute__((ext_vector_type(8))) short short8;
typedef __attribute__((ext_vector_type(4))) float f32x4;
typedef __attribute__((ext_vector_type(4))) unsigned short us4;

__device__ inline unsigned short f2bf(float f) {
    unsigned u = __float_as_uint(f);
    u = (u + 0x7FFFu + ((u >> 16) & 1u)) >> 16;   // RNE
    return (unsigned short)u;
}

__device__ inline void gload_lds16(const unsigned short* g, unsigned short* l) {
    __builtin_amdgcn_global_load_lds(
        (const __attribute__((address_space(1))) unsigned int*)(g),
        (__attribute__((address_space(3))) unsigned int*)(l),
        16, 0, 0);
}

// ---------------- elementwise convert x -> bf16 ----------------
__global__ __launch_bounds__(256) void cvt_x_kernel(const float* __restrict__ in,
                                                    unsigned short* __restrict__ out, int n4) {
    int i = blockIdx.x * 256 + threadIdx.x;
    if (i >= n4) return;
    float4 v = reinterpret_cast<const float4*>(in)[i];
    us4 o = { f2bf(v.x), f2bf(v.y), f2bf(v.z), f2bf(v.w) };
    reinterpret_cast<us4*>(out)[i] = o;
}

// ---------------- transpose + convert gate_w [K,N] f32 -> WT [N,K] bf16 ----------------
__global__ __launch_bounds__(256) void transpose_w_kernel(const float* __restrict__ W,
                                                          unsigned short* __restrict__ WT,
                                                          int K, int N) {
    __shared__ float tile[32][33];
    int bn = blockIdx.x * 32;
    int bk = blockIdx.y * 32;
    int tx = threadIdx.x & 31;
    int ty = threadIdx.x >> 5;   // 0..7
#pragma unroll
    for (int j = 0; j < 32; j += 8)
        tile[ty + j][tx] = W[(long long)(bk + ty + j) * N + bn + tx];
    __syncthreads();
#pragma unroll
    for (int j = 0; j < 32; j += 8)
        WT[(long long)(bn + ty + j) * K + bk + tx] = f2bf(tile[tx][ty + j]);
}

// ---------------- block reduction (sum, sumsq) over 256 threads ----------------
__device__ inline void block_reduce2(float& s, float& q) {
#pragma unroll
    for (int o = 32; o > 0; o >>= 1) {
        s += __shfl_xor(s, o, 64);
        q += __shfl_xor(q, o, 64);
    }
    __shared__ float sh[8];
    int w = threadIdx.x >> 6;
    if ((threadIdx.x & 63) == 0) { sh[w] = s; sh[4 + w] = q; }
    __syncthreads();
    s = (sh[0] + sh[1]) + (sh[2] + sh[3]);
    q = (sh[4] + sh[5]) + (sh[6] + sh[7]);
}

// ---------------- row LayerNorm, D=2048, one block per row (works in-place) ----------------
__global__ __launch_bounds__(256) void ln_rows_kernel(const float* __restrict__ in, long long in_stride,
                                                      float* __restrict__ out, long long out_stride,
                                                      const float* __restrict__ gamma,
                                                      const float* __restrict__ beta) {
    const float* p = in + (long long)blockIdx.x * in_stride;
    float* q = out + (long long)blockIdx.x * out_stride;
    int t = threadIdx.x;
    float4 a = reinterpret_cast<const float4*>(p)[t];
    float4 c = reinterpret_cast<const float4*>(p)[t + 256];
    float s  = (a.x + a.y) + (a.z + a.w) + (c.x + c.y) + (c.z + c.w);
    float ss = a.x*a.x + a.y*a.y + a.z*a.z + a.w*a.w
             + c.x*c.x + c.y*c.y + c.z*c.z + c.w*c.w;
    block_reduce2(s, ss);
    const float inv = 1.0f / 2048.0f;
    float mu = s * inv;
    float var = ss * inv - mu * mu;
    float rs = rsqrtf(var + 1e-6f);
    float4 g0 = reinterpret_cast<const float4*>(gamma)[t];
    float4 g1 = reinterpret_cast<const float4*>(gamma)[t + 256];
    float4 b0 = reinterpret_cast<const float4*>(beta)[t];
    float4 b1 = reinterpret_cast<const float4*>(beta)[t + 256];
    float4 o0, o1;
    o0.x = (a.x - mu) * rs * g0.x + b0.x;
    o0.y = (a.y - mu) * rs * g0.y + b0.y;
    o0.z = (a.z - mu) * rs * g0.z + b0.z;
    o0.w = (a.w - mu) * rs * g0.w + b0.w;
    o1.x = (c.x - mu) * rs * g1.x + b1.x;
    o1.y = (c.y - mu) * rs * g1.y + b1.y;
    o1.z = (c.z - mu) * rs * g1.z + b1.z;
    o1.w = (c.w - mu) * rs * g1.w + b1.w;
    reinterpret_cast<float4*>(q)[t] = o0;
    reinterpret_cast<float4*>(q)[t + 256] = o1;
}

// ---------------- exact GELU ----------------
__global__ __launch_bounds__(256) void gelu_kernel(float* __restrict__ h, int n) {
    int i = blockIdx.x * 256 + threadIdx.x;
    if (i < n) {
        float v = h[i];
        h[i] = 0.5f * v * (1.0f + erff(v * 0.70710678118654752f));
    }
}

// ---------------- batch-4 GEMV: out[4][N] += in[4][K] @ W[K][N] + bias (split-K, atomic) ----
// thread owns 4 consecutive outputs (float4 of W); blockIdx.y==0 adds the bias.
__global__ __launch_bounds__(256) void gemv4_kernel(const float* __restrict__ in,
                                                    const float* __restrict__ W,
                                                    const float* __restrict__ bias,
                                                    float* __restrict__ out,
                                                    int K, int N, int KC) {
    const int n4 = blockIdx.x * 256 + threadIdx.x;   // float4 index
    const int n = n4 * 4;
    const int k0 = blockIdx.y * KC;
    const float4* W4 = reinterpret_cast<const float4*>(W);
    const float* i0 = in;
    const float* i1 = in + K;
    const float* i2 = in + 2 * K;
    const float* i3 = in + 3 * K;
    float4 a0 = {0.f, 0.f, 0.f, 0.f}, a1 = a0, a2 = a0, a3 = a0;
#pragma unroll 4
    for (int k = k0; k < k0 + KC; ++k) {
        float4 w = W4[((long long)k * N + n) >> 2];
        float c0 = i0[k], c1 = i1[k], c2 = i2[k], c3 = i3[k];
        a0.x = fmaf(c0, w.x, a0.x); a0.y = fmaf(c0, w.y, a0.y);
        a0.z = fmaf(c0, w.z, a0.z); a0.w = fmaf(c0, w.w, a0.w);
        a1.x = fmaf(c1, w.x, a1.x); a1.y = fmaf(c1, w.y, a1.y);
        a1.z = fmaf(c1, w.z, a1.z); a1.w = fmaf(c1, w.w, a1.w);
        a2.x = fmaf(c2, w.x, a2.x); a2.y = fmaf(c2, w.y, a2.y);
        a2.z = fmaf(c2, w.z, a2.z); a2.w = fmaf(c2, w.w, a2.w);
        a3.x = fmaf(c3, w.x, a3.x); a3.y = fmaf(c3, w.y, a3.y);
        a3.z = fmaf(c3, w.z, a3.z); a3.w = fmaf(c3, w.w, a3.w);
    }
    if (blockIdx.y == 0) {
        float4 b = reinterpret_cast<const float4*>(bias)[n4];
        a0.x += b.x; a0.y += b.y; a0.z += b.z; a0.w += b.w;
        a1.x += b.x; a1.y += b.y; a1.z += b.z; a1.w += b.w;
        a2.x += b.x; a2.y += b.y; a2.z += b.z; a2.w += b.w;
        a3.x += b.x; a3.y += b.y; a3.z += b.z; a3.w += b.w;
    }
    atomicAdd(&out[n + 0], a0.x); atomicAdd(&out[n + 1], a0.y);
    atomicAdd(&out[n + 2], a0.z); atomicAdd(&out[n + 3], a0.w);
    atomicAdd(&out[N + n + 0], a1.x); atomicAdd(&out[N + n + 1], a1.y);
    atomicAdd(&out[N + n + 2], a1.z); atomicAdd(&out[N + n + 3], a1.w);
    atomicAdd(&out[2 * N + n + 0], a2.x); atomicAdd(&out[2 * N + n + 1], a2.y);
    atomicAdd(&out[2 * N + n + 2], a2.z); atomicAdd(&out[2 * N + n + 3], a2.w);
    atomicAdd(&out[3 * N + n + 0], a3.x); atomicAdd(&out[3 * N + n + 1], a3.y);
    atomicAdd(&out[3 * N + n + 2], a3.z); atomicAdd(&out[3 * N + n + 3], a3.w);
}

// ---------------- big fused kernel: pre = x + sigmoid(x@gate_w + gate_b) * bcast ----------
// m97 structure: global_load_lds width-16 staging, linear LDS, 2 barriers per K-step.
__global__ __launch_bounds__(256) void gate_gemm_kernel(const unsigned short* __restrict__ A,
                                                        const unsigned short* __restrict__ BT,
                                                        const float* __restrict__ xf,
                                                        const float* __restrict__ gate_b,
                                                        const float* __restrict__ bcast,
                                                        float* __restrict__ pre,
                                                        int M, int N, int K) {
    __shared__ unsigned short As[128 * 32];
    __shared__ unsigned short Bs[128 * 32];
    const int tid = threadIdx.x;
    const int lane = tid & 63;
    const int wave = tid >> 6;
    const int wr = wave >> 1, wc = wave & 1;          // 2x2 waves, each 64x64
    const long long row0 = (long long)blockIdx.x * 128;
    const long long col0 = (long long)blockIdx.y * 128;

    // staging: 512 chunks of 16B per tile. wave w owns chunks [w*128, w*128+128),
    // two global_load_lds calls of 64 chunks each (lane i -> base+lane*16 implicit).
    const int cb = wave * 128;
    const int ch0 = cb + lane, ch1 = cb + 64 + lane;
    unsigned short* lA0 = &As[cb * 8];
    unsigned short* lA1 = &As[(cb + 64) * 8];
    unsigned short* lB0 = &Bs[cb * 8];
    unsigned short* lB1 = &Bs[(cb + 64) * 8];
    const unsigned short* gA0 = A + (row0 + (ch0 >> 2)) * (long long)K + (ch0 & 3) * 8;
    const unsigned short* gA1 = A + (row0 + (ch1 >> 2)) * (long long)K + (ch1 & 3) * 8;
    const unsigned short* gB0 = BT + (col0 + (ch0 >> 2)) * (long long)K + (ch0 & 3) * 8;
    const unsigned short* gB1 = BT + (col0 + (ch1 >> 2)) * (long long)K + (ch1 & 3) * 8;

    f32x4 acc[4][4];
#pragma unroll
    for (int i = 0; i < 4; ++i)
#pragma unroll
        for (int j = 0; j < 4; ++j)
#pragma unroll
            for (int r = 0; r < 4; ++r) acc[i][j][r] = 0.f;

    const int r16 = lane & 15, kq = lane >> 4;

    for (int k0i = 0; k0i < K; k0i += 32) {
        gload_lds16(gA0 + k0i, lA0);
        gload_lds16(gA1 + k0i, lA1);
        gload_lds16(gB0 + k0i, lB0);
        gload_lds16(gB1 + k0i, lB1);
        __syncthreads();   // vmcnt(0) drain + all waves' staging visible
        short8 af[4], bf[4];
#pragma unroll
        for (int mi = 0; mi < 4; ++mi)
            af[mi] = *reinterpret_cast<const short8*>(&As[(wr * 64 + mi * 16 + r16) * 32 + kq * 8]);
#pragma unroll
        for (int ni = 0; ni < 4; ++ni)
            bf[ni] = *reinterpret_cast<const short8*>(&Bs[(wc * 64 + ni * 16 + r16) * 32 + kq * 8]);
#pragma unroll
        for (int mi = 0; mi < 4; ++mi)
#pragma unroll
            for (int ni = 0; ni < 4; ++ni)
                acc[mi][ni] = __builtin_amdgcn_mfma_f32_16x16x32_bf16(af[mi], bf[ni], acc[mi][ni], 0, 0, 0);
        __syncthreads();   // LDS reads done before next k-step overwrites
    }

    // epilogue: sigmoid gate, residual add, broadcast thought
#pragma unroll
    for (int mi = 0; mi < 4; ++mi) {
#pragma unroll
        for (int ni = 0; ni < 4; ++ni) {
            const long long col = col0 + wc * 64 + ni * 16 + r16;
            const float gb = gate_b[col];
#pragma unroll
            for (int r = 0; r < 4; ++r) {
                const long long row = row0 + wr * 64 + mi * 16 + kq * 4 + r;
                const float v = acc[mi][ni][r] + gb;
                const float g = 1.0f / (1.0f + __expf(-v));
                const int b = (int)(row >> 12);           // L = 4096
                const long long off = row * N + col;
                pre[off] = xf[off] + g * bcast[(long long)b * N + col];
            }
        }
    }
}

extern "C" void kernel_launch(void* const* d_in, const int* in_sizes, int n_in,
                              void* d_out, int out_size, void* d_ws, size_t ws_size,
                              hipStream_t stream) {
    const float* x         = (const float*)d_in[0];
    const float* in_gamma  = (const float*)d_in[1];
    const float* in_beta   = (const float*)d_in[2];
    const float* agg_w     = (const float*)d_in[3];
    const float* agg_b     = (const float*)d_in[4];
    const float* pn_gamma  = (const float*)d_in[5];
    const float* pn_beta   = (const float*)d_in[6];
    const float* d1_w      = (const float*)d_in[7];
    const float* d1_b      = (const float*)d_in[8];
    const float* d2_w      = (const float*)d_in[9];
    const float* d2_b      = (const float*)d_in[10];
    const float* bc_w      = (const float*)d_in[11];
    const float* bc_b      = (const float*)d_in[12];
    const float* gate_w    = (const float*)d_in[13];
    const float* gate_b    = (const float*)d_in[14];
    const float* out_gamma = (const float*)d_in[15];
    const float* out_beta  = (const float*)d_in[16];

    const int B = 4, L = 4096, D = 2048, H = 8192;
    const int M = B * L;                       // 16384
    float* out = (float*)d_out;

    char* ws = (char*)d_ws;
    unsigned short* xb  = (unsigned short*)ws;                 // 64 MB  bf16 x
    unsigned short* gwT = (unsigned short*)(ws + 67108864);    //  8 MB  bf16 gate_w^T
    float* tln   = (float*)(ws + 75497472);                    // [4][D]
    float* tbuf  = tln + 4 * D;                                // [4][D] thought
    float* hbuf  = tbuf + 4 * D;                               // [4][H]
    float* bcast = hbuf + 4 * H;                               // [4][D]

    // ---- thought chain ----
    ln_rows_kernel<<<dim3(B), dim3(256), 0, stream>>>(
        x + (long long)(L - 1) * D, (long long)L * D, tln, (long long)D, in_gamma, in_beta);
    hipMemsetAsync(tbuf, 0, 4 * D * sizeof(float), stream);
    gemv4_kernel<<<dim3(D / 1024, 64), dim3(256), 0, stream>>>(tln, agg_w, agg_b, tbuf, D, D, 32);

    for (int s = 0; s < 4; ++s) {
        ln_rows_kernel<<<dim3(B), dim3(256), 0, stream>>>(
            tbuf, (long long)D, tln, (long long)D, pn_gamma, pn_beta);
        hipMemsetAsync(hbuf, 0, 4 * H * sizeof(float), stream);
        gemv4_kernel<<<dim3(H / 1024, 32), dim3(256), 0, stream>>>(tln, d1_w, d1_b, hbuf, D, H, 64);
        gelu_kernel<<<dim3(B * H / 256), dim3(256), 0, stream>>>(hbuf, B * H);
        // residual accumulate directly into live tbuf (no zero, no add_bias)
        gemv4_kernel<<<dim3(D / 1024, 128), dim3(256), 0, stream>>>(hbuf, d2_w, d2_b, tbuf, H, D, 64);
    }
    hipMemsetAsync(bcast, 0, 4 * D * sizeof(float), stream);
    gemv4_kernel<<<dim3(D / 1024, 64), dim3(256), 0, stream>>>(tbuf, bc_w, bc_b, bcast, D, D, 32);

    // ---- prepare bf16 operands for the big GEMM ----
    cvt_x_kernel<<<dim3((M * D / 4) / 256), dim3(256), 0, stream>>>(x, xb, M * D / 4);
    transpose_w_kernel<<<dim3(D / 32, D / 32), dim3(256), 0, stream>>>(gate_w, gwT, D, D);

    // ---- fused gate GEMM + sigmoid + residual + broadcast -> d_out (pre-LN) ----
    gate_gemm_kernel<<<dim3(M / 128, D / 128), dim3(256), 0, stream>>>(
        xb, gwT, x, gate_b, bcast, out, M, D, D);

    // ---- final LayerNorm in-place on d_out ----
    ln_rows_kernel<<<dim3(M), dim3(256), 0, stream>>>(
        out, (long long)D, out, (long long)D, out_gamma, out_beta);
}

// Round 4
// 559.128 us; speedup vs baseline: 2.4632x; 1.1609x over previous
//
#include <hip/hip_runtime.h>
#include <stdint.h>

typedef __attribute__((ext_vector_type(8))) short short8;
typedef __attribute__((ext_vector_type(4))) float f32x4;
typedef __attribute__((ext_vector_type(4))) unsigned short us4;

__device__ inline unsigned short f2bf(float f) {
    unsigned u = __float_as_uint(f);
    u = (u + 0x7FFFu + ((u >> 16) & 1u)) >> 16;   // RNE
    return (unsigned short)u;
}

__device__ inline void gload_lds16(const unsigned short* g, const unsigned short* l) {
    __builtin_amdgcn_global_load_lds(
        (const __attribute__((address_space(1))) unsigned int*)(g),
        (__attribute__((address_space(3))) unsigned int*)(l),
        16, 0, 0);
}

// ---------------- elementwise convert x -> bf16 ----------------
__global__ __launch_bounds__(256) void cvt_x_kernel(const float* __restrict__ in,
                                                    unsigned short* __restrict__ out, int n4) {
    int i = blockIdx.x * 256 + threadIdx.x;
    if (i >= n4) return;
    float4 v = reinterpret_cast<const float4*>(in)[i];
    us4 o = { f2bf(v.x), f2bf(v.y), f2bf(v.z), f2bf(v.w) };
    reinterpret_cast<us4*>(out)[i] = o;
}

// ---------------- transpose + convert gate_w [K,N] f32 -> WT [N,K] bf16 ----------------
__global__ __launch_bounds__(256) void transpose_w_kernel(const float* __restrict__ W,
                                                          unsigned short* __restrict__ WT,
                                                          int K, int N) {
    __shared__ float tile[32][33];
    int bn = blockIdx.x * 32;
    int bk = blockIdx.y * 32;
    int tx = threadIdx.x & 31;
    int ty = threadIdx.x >> 5;   // 0..7
#pragma unroll
    for (int j = 0; j < 32; j += 8)
        tile[ty + j][tx] = W[(long long)(bk + ty + j) * N + bn + tx];
    __syncthreads();
#pragma unroll
    for (int j = 0; j < 32; j += 8)
        WT[(long long)(bn + ty + j) * K + bk + tx] = f2bf(tile[tx][ty + j]);
}

// ---------------- block reduction (sum, sumsq) over 256 threads ----------------
__device__ inline void block_reduce2(float& s, float& q) {
#pragma unroll
    for (int o = 32; o > 0; o >>= 1) {
        s += __shfl_xor(s, o, 64);
        q += __shfl_xor(q, o, 64);
    }
    __shared__ float sh[8];
    int w = threadIdx.x >> 6;
    if ((threadIdx.x & 63) == 0) { sh[w] = s; sh[4 + w] = q; }
    __syncthreads();
    s = (sh[0] + sh[1]) + (sh[2] + sh[3]);
    q = (sh[4] + sh[5]) + (sh[6] + sh[7]);
}

// ---------------- row LayerNorm, D=2048, one block per row (works in-place) ----------------
__global__ __launch_bounds__(256) void ln_rows_kernel(const float* __restrict__ in, long long in_stride,
                                                      float* __restrict__ out, long long out_stride,
                                                      const float* __restrict__ gamma,
                                                      const float* __restrict__ beta) {
    const float* p = in + (long long)blockIdx.x * in_stride;
    float* q = out + (long long)blockIdx.x * out_stride;
    int t = threadIdx.x;
    float4 a = reinterpret_cast<const float4*>(p)[t];
    float4 c = reinterpret_cast<const float4*>(p)[t + 256];
    float s  = (a.x + a.y) + (a.z + a.w) + (c.x + c.y) + (c.z + c.w);
    float ss = a.x*a.x + a.y*a.y + a.z*a.z + a.w*a.w
             + c.x*c.x + c.y*c.y + c.z*c.z + c.w*c.w;
    block_reduce2(s, ss);
    const float inv = 1.0f / 2048.0f;
    float mu = s * inv;
    float var = ss * inv - mu * mu;
    float rs = rsqrtf(var + 1e-6f);
    float4 g0 = reinterpret_cast<const float4*>(gamma)[t];
    float4 g1 = reinterpret_cast<const float4*>(gamma)[t + 256];
    float4 b0 = reinterpret_cast<const float4*>(beta)[t];
    float4 b1 = reinterpret_cast<const float4*>(beta)[t + 256];
    float4 o0, o1;
    o0.x = (a.x - mu) * rs * g0.x + b0.x;
    o0.y = (a.y - mu) * rs * g0.y + b0.y;
    o0.z = (a.z - mu) * rs * g0.z + b0.z;
    o0.w = (a.w - mu) * rs * g0.w + b0.w;
    o1.x = (c.x - mu) * rs * g1.x + b1.x;
    o1.y = (c.y - mu) * rs * g1.y + b1.y;
    o1.z = (c.z - mu) * rs * g1.z + b1.z;
    o1.w = (c.w - mu) * rs * g1.w + b1.w;
    reinterpret_cast<float4*>(q)[t] = o0;
    reinterpret_cast<float4*>(q)[t + 256] = o1;
}

// ---------------- exact GELU ----------------
__global__ __launch_bounds__(256) void gelu_kernel(float* __restrict__ h, int n) {
    int i = blockIdx.x * 256 + threadIdx.x;
    if (i < n) {
        float v = h[i];
        h[i] = 0.5f * v * (1.0f + erff(v * 0.70710678118654752f));
    }
}

// ---------------- batch-4 GEMV: out[4][N] += in[4][K] @ W[K][N] + bias (split-K, atomic) ----
__global__ __launch_bounds__(256) void gemv4_kernel(const float* __restrict__ in,
                                                    const float* __restrict__ W,
                                                    const float* __restrict__ bias,
                                                    float* __restrict__ out,
                                                    int K, int N, int KC) {
    const int n4 = blockIdx.x * 256 + threadIdx.x;   // float4 index
    const int n = n4 * 4;
    const int k0 = blockIdx.y * KC;
    const float4* W4 = reinterpret_cast<const float4*>(W);
    const float* i0 = in;
    const float* i1 = in + K;
    const float* i2 = in + 2 * K;
    const float* i3 = in + 3 * K;
    float4 a0 = {0.f, 0.f, 0.f, 0.f}, a1 = a0, a2 = a0, a3 = a0;
#pragma unroll 4
    for (int k = k0; k < k0 + KC; ++k) {
        float4 w = W4[((long long)k * N + n) >> 2];
        float c0 = i0[k], c1 = i1[k], c2 = i2[k], c3 = i3[k];
        a0.x = fmaf(c0, w.x, a0.x); a0.y = fmaf(c0, w.y, a0.y);
        a0.z = fmaf(c0, w.z, a0.z); a0.w = fmaf(c0, w.w, a0.w);
        a1.x = fmaf(c1, w.x, a1.x); a1.y = fmaf(c1, w.y, a1.y);
        a1.z = fmaf(c1, w.z, a1.z); a1.w = fmaf(c1, w.w, a1.w);
        a2.x = fmaf(c2, w.x, a2.x); a2.y = fmaf(c2, w.y, a2.y);
        a2.z = fmaf(c2, w.z, a2.z); a2.w = fmaf(c2, w.w, a2.w);
        a3.x = fmaf(c3, w.x, a3.x); a3.y = fmaf(c3, w.y, a3.y);
        a3.z = fmaf(c3, w.z, a3.z); a3.w = fmaf(c3, w.w, a3.w);
    }
    if (blockIdx.y == 0) {
        float4 b = reinterpret_cast<const float4*>(bias)[n4];
        a0.x += b.x; a0.y += b.y; a0.z += b.z; a0.w += b.w;
        a1.x += b.x; a1.y += b.y; a1.z += b.z; a1.w += b.w;
        a2.x += b.x; a2.y += b.y; a2.z += b.z; a2.w += b.w;
        a3.x += b.x; a3.y += b.y; a3.z += b.z; a3.w += b.w;
    }
    atomicAdd(&out[n + 0], a0.x); atomicAdd(&out[n + 1], a0.y);
    atomicAdd(&out[n + 2], a0.z); atomicAdd(&out[n + 3], a0.w);
    atomicAdd(&out[N + n + 0], a1.x); atomicAdd(&out[N + n + 1], a1.y);
    atomicAdd(&out[N + n + 2], a1.z); atomicAdd(&out[N + n + 3], a1.w);
    atomicAdd(&out[2 * N + n + 0], a2.x); atomicAdd(&out[2 * N + n + 1], a2.y);
    atomicAdd(&out[2 * N + n + 2], a2.z); atomicAdd(&out[2 * N + n + 3], a2.w);
    atomicAdd(&out[3 * N + n + 0], a3.x); atomicAdd(&out[3 * N + n + 1], a3.y);
    atomicAdd(&out[3 * N + n + 2], a3.z); atomicAdd(&out[3 * N + n + 3], a3.w);
}

// ================= 256x256 8-phase gate GEMM =================
// pre = x + sigmoid(x@gate_w + gate_b) * bcast
// A [M,K] bf16, BT [N,K] bf16. 512 threads = 8 waves (2 M x 4 N), per-wave C = 128x64.
// LDS 128KB dynamic: A[2buf][2half][128][64] bf16, B same. XOR-swizzle chunk^=(row&7),
// applied on the global SOURCE (gload_lds dest is linear) and on ds_read addresses.
#define BK 64
__global__ __launch_bounds__(512, 2) void gate_gemm_kernel(const unsigned short* __restrict__ A,
                                                           const unsigned short* __restrict__ BT,
                                                           const float* __restrict__ xf,
                                                           const float* __restrict__ gate_b,
                                                           const float* __restrict__ bcast,
                                                           float* __restrict__ pre,
                                                           int M, int N, int K) {
    extern __shared__ unsigned short lds[];
    const int tid = threadIdx.x;
    const int lane = tid & 63;
    const int wave = tid >> 6;            // 0..7
    const int wm = wave >> 2;             // 0..1  (M half)
    const int wn = wave & 3;              // 0..3  (N quarter)
    const int bm0 = blockIdx.x * 256;
    const int bn0 = blockIdx.y * 256;
    const int NT = K / BK;                // K-tiles

    // ---- staging geometry: half-tile = 128 rows x 64 cols bf16 = 1024 chunks of 16B.
    // wave w, issue j covers chunks [j*512 + w*64, +64). dest linear; source col-chunk
    // XORed with (row&7) so LDS holds the swizzled layout.
    const int ch0 = wave * 64 + lane;
    const int ch1 = 512 + wave * 64 + lane;
    const int r0 = ch0 >> 3, c0s = (ch0 & 7) ^ (r0 & 7);
    const int r1 = ch1 >> 3, c1s = (ch1 & 7) ^ (r1 & 7);
    const int srcoff0 = r0 * K + c0s * 8;     // element offset
    const int srcoff1 = r1 * K + c1s * 8;
    const int ldso0 = ch0 * 8;                // ushort offset within half-buffer
    const int ldso1 = ch1 * 8;

    // half-buffer bases (ushort idx): A: buf*16384 + h*8192 ; B: +32768
    const unsigned short* Abase = A + (long long)bm0 * K;
    const unsigned short* Bbase = BT + (long long)bn0 * K;

#define STAGE_A(buf, h, t)  do { \
        const unsigned short* g = Abase + (h) * 128 * K + (t) * BK; \
        const unsigned short* d = &lds[(buf) * 16384 + (h) * 8192]; \
        gload_lds16(g + srcoff0, d + ldso0); \
        gload_lds16(g + srcoff1, d + ldso1); } while (0)
#define STAGE_B(buf, h, t)  do { \
        const unsigned short* g = Bbase + (h) * 128 * K + (t) * BK; \
        const unsigned short* d = &lds[32768 + (buf) * 16384 + (h) * 8192]; \
        gload_lds16(g + srcoff0, d + ldso0); \
        gload_lds16(g + srcoff1, d + ldso1); } while (0)

    f32x4 acc[8][4];
#pragma unroll
    for (int i = 0; i < 8; ++i)
#pragma unroll
        for (int j = 0; j < 4; ++j)
#pragma unroll
            for (int r = 0; r < 4; ++r) acc[i][j][r] = 0.f;

    const int r16 = lane & 15, kq = lane >> 4;
    const int bwrow = (wn & 1) * 64;          // B row base within half

    // ---- prologue: stage tile 0 -> buf 0, full drain once
    STAGE_A(0, 0, 0); STAGE_A(0, 1, 0);
    STAGE_B(0, 0, 0); STAGE_B(0, 1, 0);
    asm volatile("s_waitcnt vmcnt(0)" ::: "memory");
    __builtin_amdgcn_s_barrier();

    for (int t = 0; t < NT; ++t) {
        const int p = t & 1;
        const int u = t + 1;                  // tile staged during this tile -> buf 1-p
        const int a_base = p * 16384 + wm * 8192;
        const int b_base = 32768 + p * 16384 + (wn >> 1) * 8192;

#pragma unroll
        for (int q = 0; q < 4; ++q) {
            const int mh = (q >> 1) * 4;      // mi quadrant base
            const int nh = (q & 1) * 2;       // ni quadrant base
            short8 af[4][2], bf[2][2];
#pragma unroll
            for (int mi = 0; mi < 4; ++mi) {
                const int rl = (mh + mi) * 16 + r16;
#pragma unroll
                for (int kk = 0; kk < 2; ++kk)
                    af[mi][kk] = *reinterpret_cast<const short8*>(
                        &lds[a_base + rl * 64 + (((kk << 2) | kq) ^ (rl & 7)) * 8]);
            }
#pragma unroll
            for (int ni = 0; ni < 2; ++ni) {
                const int rl = bwrow + (nh + ni) * 16 + r16;
#pragma unroll
                for (int kk = 0; kk < 2; ++kk)
                    bf[ni][kk] = *reinterpret_cast<const short8*>(
                        &lds[b_base + rl * 64 + (((kk << 2) | kq) ^ (rl & 7)) * 8]);
            }
            if (q == 0 && u < NT) { STAGE_A(1 - p, 0, u); STAGE_A(1 - p, 1, u); }
            if (q == 1 && u < NT) { STAGE_B(1 - p, 0, u); STAGE_B(1 - p, 1, u); }
            __builtin_amdgcn_s_barrier();
            __builtin_amdgcn_s_setprio(1);
#pragma unroll
            for (int mi = 0; mi < 4; ++mi)
#pragma unroll
                for (int ni = 0; ni < 2; ++ni)
#pragma unroll
                    for (int kk = 0; kk < 2; ++kk)
                        acc[mh + mi][nh + ni] = __builtin_amdgcn_mfma_f32_16x16x32_bf16(
                            af[mi][kk], bf[ni][kk], acc[mh + mi][nh + ni], 0, 0, 0);
            __builtin_amdgcn_s_setprio(0);
            if (q == 3) asm volatile("s_waitcnt vmcnt(0)" ::: "memory");  // tile u landed
            __builtin_amdgcn_s_barrier();
        }
    }

    // ---- epilogue: sigmoid gate, residual add, broadcast thought
    const int bnum = bm0 >> 12;               // batch (L=4096, BM=256 divides)
    const float* bc_row = bcast + (long long)bnum * N;
#pragma unroll
    for (int mi = 0; mi < 8; ++mi) {
        const int row = bm0 + wm * 128 + mi * 16 + kq * 4;
#pragma unroll
        for (int ni = 0; ni < 4; ++ni) {
            const int col = bn0 + wn * 64 + ni * 16 + r16;
            const float gb = gate_b[col];
            const float bc = bc_row[col];
#pragma unroll
            for (int r = 0; r < 4; ++r) {
                const long long off = (long long)(row + r) * N + col;
                const float v = acc[mi][ni][r] + gb;
                const float g = 1.0f / (1.0f + __expf(-v));
                pre[off] = xf[off] + g * bc;
            }
        }
    }
}
#undef STAGE_A
#undef STAGE_B

extern "C" void kernel_launch(void* const* d_in, const int* in_sizes, int n_in,
                              void* d_out, int out_size, void* d_ws, size_t ws_size,
                              hipStream_t stream) {
    const float* x         = (const float*)d_in[0];
    const float* in_gamma  = (const float*)d_in[1];
    const float* in_beta   = (const float*)d_in[2];
    const float* agg_w     = (const float*)d_in[3];
    const float* agg_b     = (const float*)d_in[4];
    const float* pn_gamma  = (const float*)d_in[5];
    const float* pn_beta   = (const float*)d_in[6];
    const float* d1_w      = (const float*)d_in[7];
    const float* d1_b      = (const float*)d_in[8];
    const float* d2_w      = (const float*)d_in[9];
    const float* d2_b      = (const float*)d_in[10];
    const float* bc_w      = (const float*)d_in[11];
    const float* bc_b      = (const float*)d_in[12];
    const float* gate_w    = (const float*)d_in[13];
    const float* gate_b    = (const float*)d_in[14];
    const float* out_gamma = (const float*)d_in[15];
    const float* out_beta  = (const float*)d_in[16];

    const int B = 4, L = 4096, D = 2048, H = 8192;
    const int M = B * L;                       // 16384
    float* out = (float*)d_out;

    char* ws = (char*)d_ws;
    unsigned short* xb  = (unsigned short*)ws;                 // 64 MB  bf16 x
    unsigned short* gwT = (unsigned short*)(ws + 67108864);    //  8 MB  bf16 gate_w^T
    float* tln   = (float*)(ws + 75497472);                    // [4][D]
    float* tbuf  = tln + 4 * D;                                // [4][D] thought
    float* hbuf  = tbuf + 4 * D;                               // [4][H]
    float* bcast = hbuf + 4 * H;                               // [4][D]

    // allow 128KB dynamic LDS for the 8-phase GEMM (idempotent, non-stream call)
    static bool attr_done = false;
    if (!attr_done) {
        hipFuncSetAttribute((const void*)gate_gemm_kernel,
                            hipFuncAttributeMaxDynamicSharedMemorySize, 131072);
        attr_done = true;
    }

    // ---- thought chain ----
    ln_rows_kernel<<<dim3(B), dim3(256), 0, stream>>>(
        x + (long long)(L - 1) * D, (long long)L * D, tln, (long long)D, in_gamma, in_beta);
    hipMemsetAsync(tbuf, 0, 4 * D * sizeof(float), stream);
    gemv4_kernel<<<dim3(D / 1024, 64), dim3(256), 0, stream>>>(tln, agg_w, agg_b, tbuf, D, D, 32);

    for (int s = 0; s < 4; ++s) {
        ln_rows_kernel<<<dim3(B), dim3(256), 0, stream>>>(
            tbuf, (long long)D, tln, (long long)D, pn_gamma, pn_beta);
        hipMemsetAsync(hbuf, 0, 4 * H * sizeof(float), stream);
        gemv4_kernel<<<dim3(H / 1024, 32), dim3(256), 0, stream>>>(tln, d1_w, d1_b, hbuf, D, H, 64);
        gelu_kernel<<<dim3(B * H / 256), dim3(256), 0, stream>>>(hbuf, B * H);
        gemv4_kernel<<<dim3(D / 1024, 128), dim3(256), 0, stream>>>(hbuf, d2_w, d2_b, tbuf, H, D, 64);
    }
    hipMemsetAsync(bcast, 0, 4 * D * sizeof(float), stream);
    gemv4_kernel<<<dim3(D / 1024, 64), dim3(256), 0, stream>>>(tbuf, bc_w, bc_b, bcast, D, D, 32);

    // ---- prepare bf16 operands for the big GEMM ----
    cvt_x_kernel<<<dim3((M * D / 4) / 256), dim3(256), 0, stream>>>(x, xb, M * D / 4);
    transpose_w_kernel<<<dim3(D / 32, D / 32), dim3(256), 0, stream>>>(gate_w, gwT, D, D);

    // ---- fused gate GEMM + sigmoid + residual + broadcast -> d_out (pre-LN) ----
    gate_gemm_kernel<<<dim3(M / 256, D / 256), dim3(512), 131072, stream>>>(
        xb, gwT, x, gate_b, bcast, out, M, D, D);

    // ---- final LayerNorm in-place on d_out ----
    ln_rows_kernel<<<dim3(M), dim3(256), 0, stream>>>(
        out, (long long)D, out, (long long)D, out_gamma, out_beta);
}